// Round 22
// baseline (173.667 us; speedup 1.0000x reference)
//
#include <hip/hip_runtime.h>
#include <hip/hip_bf16.h>
#include <math.h>

#define NEG_SLOPE 0.2f
#define PACK_SHIFT 22
#define PACK_MASK ((1u << PACK_SHIFT) - 1u)
#define NWG 256          // WGs for bucket scatter
#define MAXBK 128        // max buckets (N <= 131072)
#define CAP 32768        // per-bucket staging capacity (expected ~16.4K)

typedef __attribute__((ext_vector_type(8))) short short8;
typedef __attribute__((ext_vector_type(4))) float f32x4;

__device__ __forceinline__ float leaky(float v) { return v >= 0.f ? v : NEG_SLOPE * v; }

// fp32 -> bf16 RNE (bit trick, finite inputs)
__device__ __forceinline__ short bfr(float f)
{
    union { float f; unsigned u; } v; v.f = f;
    unsigned r = (v.u + 0x7FFFu + ((v.u >> 16) & 1u)) >> 16;
    return (short)r;
}
// bf16 bits -> fp32
__device__ __forceinline__ float b2f(short s)
{
    union { unsigned u; float f; } v; v.u = ((unsigned)(unsigned short)s) << 16;
    return v.f;
}

// fp32 -> OCP e4m3fn (RNE, clamp 448, FTZ-free subnormals)
__device__ __forceinline__ unsigned char enc8(float f)
{
    union { float f; unsigned u; } v; v.f = f;
    unsigned s = (v.u >> 24) & 0x80u;
    v.u &= 0x7FFFFFFFu;
    if (v.f >= 448.f) return (unsigned char)(s | 0x7Eu);       // 448
    if (v.f < 0.015625f) {                                     // subnormal: k * 2^-9
        int mm = (int)rintf(v.f * 512.f);                      // 0..8 (8 carries to 2^-6)
        return (unsigned char)(s | (unsigned)mm);
    }
    unsigned u = v.u + 0x7FFFFu + ((v.u >> 20) & 1u);          // RNE to 3-bit mantissa
    unsigned e = ((u >> 23) & 0xFFu) - 120u;
    unsigned m = (u >> 20) & 7u;
    return (unsigned char)(s | (e << 3) | m);
}

// e4m3fn -> fp32
__device__ __forceinline__ float dec8(unsigned b)
{
#if __has_builtin(__builtin_amdgcn_cvt_f32_fp8)
    return __builtin_amdgcn_cvt_f32_fp8((int)b, 0);
#else
    unsigned s = (b & 0x80u) << 24, em = b & 0x7Fu;
    union { unsigned u; float f; } n; n.u = s | (((em >> 3) + 120u) << 23) | ((em & 7u) << 20);
    union { unsigned u; float f; } t; t.f = (float)em * 0.001953125f; t.u |= s;
    return em >= 8u ? n.f : t.f;
#endif
}

// ---------------- setup: W1/W2 fragment-packed bf16, w2a/w2d, detect, gcur ----------
__global__ void setup_kernel(const float* __restrict__ W1, const float* __restrict__ W2,
                             const float* __restrict__ as2, const float* __restrict__ ad2,
                             const unsigned* __restrict__ eraw,
                             short* __restrict__ W1P, short* __restrict__ W2P,
                             float* __restrict__ w2a, float* __restrict__ w2d,
                             int* __restrict__ flag, int* __restrict__ gcur)
{
    int bid = blockIdx.x, t = threadIdx.x;
    if (bid < 64) {                       // W1P: 16384 shorts
        int id = bid * 256 + t;
        int j = id & 7, l = (id >> 3) & 63, fr = id >> 9;
        int ks = fr >> 2, nt = fr & 3;
        int k = ks * 32 + (l >> 4) * 8 + j;
        int c = nt * 16 + (l & 15);
        W1P[id] = bfr(W1[k * 64 + c]);
    } else if (bid < 76) {                // W2P: 3072 shorts (12 blocks)
        int id = (bid - 64) * 256 + t;
        if (id < 3072) {
            int j = id & 7, l = (id >> 3) & 63, fr = id >> 9;
            int ks = fr / 3, nt = fr - ks * 3;
            int k = ks * 32 + (l >> 4) * 8 + j;
            int c = nt * 16 + (l & 15);
            W2P[id] = (c < 40) ? bfr(W2[k * 40 + c]) : (short)0;
        }
    } else if (bid == 76) {               // w2a/w2d + gcur zero
        if (t < 64) {
            float a = 0.f, d = 0.f;
            for (int c = 0; c < 40; ++c) {
                float w = W2[t * 40 + c];
                a += w * as2[c];
                d += w * ad2[c];
            }
            w2a[t] = a; w2d[t] = d;
        } else if (t < 64 + MAXBK) {
            gcur[t - 64] = 0;
        }
    } else {                              // detect int64 vs int32 edge layout
        __shared__ int anynz;
        if (t == 0) anynz = 0;
        __syncthreads();
        bool nz = false;
#pragma unroll
        for (int j = 0; j < 8; ++j) {
            int idx = 2 * (t + 256 * j) + 1;
            nz |= (eraw[idx] != 0u);
        }
        if (nz) anynz = 1;
        __syncthreads();
        if (t == 0) *flag = anynz ? 0 : 1;     // 1 => int64 layout
    }
}

// ---------------- fused1: blocks [0,NWG) = scat1' (hist+reserve+scatter);
// ----------------         blocks [NWG,..) = gemm1 (128-row tile, B-frag sharing) -----
__global__ __launch_bounds__(256) void fused1_kernel(
    // gemm1 args
    const float* __restrict__ x, const short* __restrict__ W1P,
    const float* __restrict__ as1, const float* __restrict__ ad1,
    unsigned char* __restrict__ h1q, short* __restrict__ als1h,
    float* __restrict__ ald1, int N,
    // scat1' args
    const unsigned* __restrict__ eraw, const int* __restrict__ flag,
    int* __restrict__ gcur, unsigned* __restrict__ stage, int NBK, int E)
{
    __shared__ short xsb[128 * 128];      // 32 KB: x K-half bf16, slot^=(row&7); reused for epilogue
    __shared__ int cnt[MAXBK];
    __shared__ int st[MAXBK];
    const int t = threadIdx.x;

    if (blockIdx.x < NWG) {
        // ---- scat1': one-pass bucket scatter with per-WG range reservation ----
        int wg = blockIdx.x;
        if (t < NBK) cnt[t] = 0;
        __syncthreads();
        int f = *flag;
        int chunk = (E + NWG - 1) / NWG;
        int lo = wg * chunk;
        int hi = lo + chunk; if (hi > E) hi = E;
        for (int e = lo + t; e < hi; e += 256) {
            int dst = (int)(f ? eraw[2 * (E + e)] : eraw[E + e]);
            atomicAdd(&cnt[dst >> 10], 1);
        }
        __syncthreads();
        if (t < NBK) {
            int c = cnt[t];
            st[t] = t * CAP + atomicAdd(&gcur[t], c);
            cnt[t] = 0;
        }
        __syncthreads();
        for (int e = lo + t; e < hi; e += 256) {
            unsigned src = f ? eraw[2 * e] : eraw[e];
            unsigned dst = f ? eraw[2 * (E + e)] : eraw[E + e];
            int b = (int)(dst >> 10);
            int k = atomicAdd(&cnt[b], 1);
            int pos = st[b] + k;
            if (pos < (b + 1) * CAP)      // safety clamp (never hit for uniform graphs)
                stage[pos] = src | ((dst & 1023u) << PACK_SHIFT);
        }
        return;
    }

    // ---- gemm1: 128-row tile; each wave owns rows m and m+16 of its 32-row band ----
    const int bid = blockIdx.x - NWG;
    const int l = t & 63, wv = t >> 6;
    const int m = l & 15, g = l >> 4;
    const int row0 = bid * 128;

    f32x4 acc[2][4] = {{f32x4{0,0,0,0}, f32x4{0,0,0,0}, f32x4{0,0,0,0}, f32x4{0,0,0,0}},
                       {f32x4{0,0,0,0}, f32x4{0,0,0,0}, f32x4{0,0,0,0}, f32x4{0,0,0,0}}};
    const int arl0 = wv * 32 + m;         // local A rows (arl&7 == m&7 for both)
    const int arl1 = arl0 + 16;

    for (int kc = 0; kc < 2; ++kc) {
        // stage x half: 128 rows x 16 slots (slot = 8 floats -> 8 bf16)
#pragma unroll
        for (int j = 0; j < 8; ++j) {
            int idx = t + 256 * j;
            int r = idx >> 4, s = idx & 15;
            int row = row0 + r;
            short8 v8 = short8{0,0,0,0,0,0,0,0};
            if (row < N) {
                const float* p = x + (size_t)row * 256 + kc * 128 + s * 8;
                float4 a = *(const float4*)p;
                float4 b = *(const float4*)(p + 4);
                v8[0] = bfr(a.x); v8[1] = bfr(a.y); v8[2] = bfr(a.z); v8[3] = bfr(a.w);
                v8[4] = bfr(b.x); v8[5] = bfr(b.y); v8[6] = bfr(b.z); v8[7] = bfr(b.w);
            }
            int sw = s ^ (r & 7);
            *(short8*)&xsb[r * 128 + sw * 8] = v8;
        }
        __syncthreads();
#pragma unroll
        for (int ksub = 0; ksub < 4; ++ksub) {
            const int ks = kc * 4 + ksub;
            const int sA = (ksub * 4 + g) ^ (m & 7);
            short8 a0 = *(const short8*)&xsb[arl0 * 128 + sA * 8];
            short8 a1 = *(const short8*)&xsb[arl1 * 128 + sA * 8];
#pragma unroll
            for (int nt = 0; nt < 4; ++nt) {
                short8 bf_ = *(const short8*)(W1P + ((ks * 4 + nt) * 64 + l) * 8);
                acc[0][nt] = __builtin_amdgcn_mfma_f32_16x16x32_bf16(a0, bf_, acc[0][nt], 0, 0, 0);
                acc[1][nt] = __builtin_amdgcn_mfma_f32_16x16x32_bf16(a1, bf_, acc[1][nt], 0, 0, 0);
            }
        }
        __syncthreads();
    }

    // epilogue 1: per-head attention logits (both row sets)
    float a_sv[4], a_dv[4];
#pragma unroll
    for (int nt = 0; nt < 4; ++nt) { a_sv[nt] = as1[nt * 16 + m]; a_dv[nt] = ad1[nt * 16 + m]; }

    float vs[2][4][4], vd[2][4][4];
#pragma unroll
    for (int rs = 0; rs < 2; ++rs)
#pragma unroll
        for (int nt = 0; nt < 4; ++nt)
#pragma unroll
            for (int r = 0; r < 4; ++r) {
                vs[rs][nt][r] = acc[rs][nt][r] * a_sv[nt];
                vd[rs][nt][r] = acc[rs][nt][r] * a_dv[nt];
            }
#pragma unroll
    for (int off = 1; off < 8; off <<= 1)
#pragma unroll
        for (int rs = 0; rs < 2; ++rs)
#pragma unroll
            for (int nt = 0; nt < 4; ++nt)
#pragma unroll
                for (int r = 0; r < 4; ++r) {
                    vs[rs][nt][r] += __shfl_xor(vs[rs][nt][r], off);
                    vd[rs][nt][r] += __shfl_xor(vd[rs][nt][r], off);
                }

    // epilogue 2: fp8 features via LDS bounce -> coalesced 16B stores
    unsigned char* hb = (unsigned char*)xsb;   // 8KB region (safe: all compute reads done)
#pragma unroll
    for (int rs = 0; rs < 2; ++rs)
#pragma unroll
        for (int nt = 0; nt < 4; ++nt)
#pragma unroll
            for (int r = 0; r < 4; ++r)
                hb[(wv * 32 + rs * 16 + g * 4 + r) * 64 + nt * 16 + m] = enc8(acc[rs][nt][r]);
    __syncthreads();
#pragma unroll
    for (int j = 0; j < 2; ++j) {
        int u = t + 256 * j;
        int r = u >> 2, part = u & 3;
        int row = row0 + r;
        if (row < N)
            *(uint4*)(h1q + (size_t)row * 64 + part * 16) = *(const uint4*)&hb[r * 64 + part * 16];
    }

    if ((l & 7) == 0) {
        int par = m >> 3;
#pragma unroll
        for (int rs = 0; rs < 2; ++rs) {
            int orow0 = row0 + wv * 32 + rs * 16 + g * 4;
#pragma unroll
            for (int nt = 0; nt < 4; ++nt)
#pragma unroll
                for (int r = 0; r < 4; ++r) {
                    int row = orow0 + r;
                    if (row < N) {
                        als1h[row * 8 + 2 * nt + par] = bfr(vs[rs][nt][r]);
                        ald1[row * 8 + 2 * nt + par] = vd[rs][nt][r];
                    }
                }
        }
    }
}

// ---------------- tinyscan: prefix over bucket totals -> bb -------------------------
__global__ void tinyscan_kernel(const int* __restrict__ gcur, int* __restrict__ bb, int NBK)
{
    int lane = threadIdx.x;               // 64 threads
    int v0 = (lane < NBK) ? min(gcur[lane], CAP) : 0;
    int v1 = (lane + 64 < NBK) ? min(gcur[lane + 64], CAP) : 0;
    int s0 = v0;
#pragma unroll
    for (int off = 1; off < 64; off <<= 1) { int u = __shfl_up(s0, off); if (lane >= off) s0 += u; }
    int tot0 = __shfl(s0, 63);
    if (lane < NBK) bb[lane] = s0 - v0;
    int s1 = v1;
#pragma unroll
    for (int off = 1; off < 64; off <<= 1) { int u = __shfl_up(s1, off); if (lane >= off) s1 += u; }
    if (lane + 64 < NBK) bb[lane + 64] = tot0 + s1 - v1;
    int tot1 = __shfl(s1, 63);
    if (lane == 0) bb[NBK] = tot0 + tot1;
}

// ---------------- scat2: per bucket: LDS count + scan -> rowptr; place ssorted -------
__global__ __launch_bounds__(1024) void scat2_kernel(
    const unsigned* __restrict__ stage, const int* __restrict__ gcur,
    const int* __restrict__ bb, int* __restrict__ rowptr, int* __restrict__ ssorted,
    int NBK, int N)
{
    __shared__ int cnt[1024];
    __shared__ int sc[1024];
    __shared__ int wt[16];
    int b = blockIdx.x, i = threadIdx.x;
    int cntb = min(gcur[b], CAP);
    int basein = b * CAP;
    int baseout = bb[b];
    int node0 = b << 10;
    int nvalid = N - node0; if (nvalid > 1024) nvalid = 1024;
    cnt[i] = 0;
    __syncthreads();
    for (int p = i; p < cntb; p += 1024)
        atomicAdd(&cnt[stage[basein + p] >> PACK_SHIFT], 1);
    __syncthreads();
    int v = cnt[i];
    int lane = i & 63, wv = i >> 6;
    int incl = v;
#pragma unroll
    for (int off = 1; off < 64; off <<= 1) { int u = __shfl_up(incl, off); if (lane >= off) incl += u; }
    if (lane == 63) wt[wv] = incl;
    __syncthreads();
    int wbase = 0;
    for (int w = 0; w < wv; ++w) wbase += wt[w];
    int excl = wbase + incl - v;
    sc[i] = excl;
    if (i < nvalid) rowptr[node0 + i] = baseout + excl;
    if (b == NBK - 1 && i == 0) rowptr[N] = bb[NBK];
    cnt[i] = 0;
    __syncthreads();
    for (int p = i; p < cntb; p += 1024) {
        unsigned w = stage[basein + p];
        int d = (int)(w >> PACK_SHIFT);
        int k = atomicAdd(&cnt[d], 1);
        ssorted[baseout + sc[d] + k] = (int)(w & PACK_MASK);
    }
}

// ---------------- agg1: 2 nodes/wave (ushort fp8-pair lanes) -> xq fp8 + logits ------
__global__ __launch_bounds__(256) void agg1_kernel(
    const int* __restrict__ rowptr, const int* __restrict__ srcs,
    const unsigned char* __restrict__ h1q, const short* __restrict__ als1h,
    const float* __restrict__ ald1, const float* __restrict__ b1,
    const float* __restrict__ w2a, const float* __restrict__ w2d,
    unsigned char* __restrict__ xq, float* __restrict__ al2s, float* __restrict__ al2d, int N)
{
    int t = threadIdx.x, lane = t & 63, w = t >> 6;
    int half = lane & 32;
    int cl = lane & 31;                 // channel pair index
    int n = blockIdx.x * 8 + w * 2 + (lane >> 5);
    bool alive = n < N;
    int nn = alive ? n : 0;
    int hb = cl >> 2;                   // head of channels 2cl,2cl+1
    int ph = lane & 7;                  // pe head this lane computes
    int pes = (lane >> 3) & 3;          // pe edge sub-slot

    float aldn = ald1[nn * 8 + hb];
    float aldl = ald1[nn * 8 + ph];
    float alsn = b2f(als1h[nn * 8 + hb]);
    float p = __expf(leaky(alsn + aldn));
    float den = p;
    unsigned hv0 = *(const unsigned short*)(h1q + (size_t)nn * 64 + cl * 2);
    float acc0 = p * dec8(hv0 & 0xffu);
    float acc1 = p * dec8(hv0 >> 8);

    int beg = alive ? rowptr[nn] : 0;
    int end = alive ? rowptr[nn + 1] : 0;
    int iters = (end - beg + 7) >> 3;
    int io = __shfl(iters, lane ^ 32);
    int mi = iters > io ? iters : io;

    for (int it = 0; it < mi; ++it) {
        int base = beg + it * 8;
        if (base < end) {
            int q = base + (lane & 7);
            int sv = srcs[q < end ? q : end - 1];
            float pel0, pel1;
            {
                int srcl = __shfl(sv, half + pes);
                float av = b2f(als1h[srcl * 8 + ph]);
                pel0 = (base + pes < end) ? __expf(leaky(av + aldl)) : 0.f;
            }
            {
                int srcl = __shfl(sv, half + 4 + pes);
                float av = b2f(als1h[srcl * 8 + ph]);
                pel1 = (base + 4 + pes < end) ? __expf(leaky(av + aldl)) : 0.f;
            }
            int sj[8];
#pragma unroll
            for (int j = 0; j < 8; ++j) sj[j] = __shfl(sv, half + j);
            unsigned hv[8];
#pragma unroll
            for (int j = 0; j < 8; ++j)
                hv[j] = *(const unsigned short*)(h1q + (size_t)sj[j] * 64 + cl * 2);
#pragma unroll
            for (int j = 0; j < 8; ++j) {
                float pj = __shfl(j < 4 ? pel0 : pel1, half + ((j & 3) << 3) + hb);
                den += pj;
                acc0 += pj * dec8(hv[j] & 0xffu);
                acc1 += pj * dec8(hv[j] >> 8);
            }
        }
    }
    if (alive) {
        float2 bb = *(const float2*)(b1 + cl * 2);
        float v0 = acc0 / den + bb.x;
        float v1 = acc1 / den + bb.y;
        float x0 = v0 > 0.f ? v0 : expm1f(v0);
        float x1 = v1 > 0.f ? v1 : expm1f(v1);
        unsigned pk = (unsigned)enc8(x0) | ((unsigned)enc8(x1) << 8);
        *(unsigned short*)(xq + (size_t)n * 64 + cl * 2) = (unsigned short)pk;
        float2 wa = *(const float2*)(w2a + cl * 2);
        float2 wd = *(const float2*)(w2d + cl * 2);
        float sa = x0 * wa.x + x1 * wa.y;
        float sd = x0 * wd.x + x1 * wd.y;
#pragma unroll
        for (int off = 1; off < 32; off <<= 1) {
            sa += __shfl_xor(sa, off);
            sd += __shfl_xor(sd, off);
        }
        if (cl == 0) { al2s[n] = sa; al2d[n] = sd; }
    }
}

// ---------------- agg2: 2 nodes/wave aggregate xq (fp8) -> gq bf16 -------------------
__global__ __launch_bounds__(256) void agg2_kernel(
    const int* __restrict__ rowptr, const int* __restrict__ srcs,
    const unsigned char* __restrict__ xq,
    const float* __restrict__ al2s, const float* __restrict__ al2d,
    short* __restrict__ gq, int N)
{
    int t = threadIdx.x, lane = t & 63, w = t >> 6;
    int half = lane & 32;
    int cl = lane & 31;
    int n = blockIdx.x * 8 + w * 2 + (lane >> 5);
    bool alive = n < N;
    int nn = alive ? n : 0;

    float dn = al2d[nn];
    float p = __expf(leaky(al2s[nn] + dn));
    float den = p;
    unsigned hv0 = *(const unsigned short*)(xq + (size_t)nn * 64 + cl * 2);
    float acc0 = p * dec8(hv0 & 0xffu);
    float acc1 = p * dec8(hv0 >> 8);

    int beg = alive ? rowptr[nn] : 0;
    int end = alive ? rowptr[nn + 1] : 0;
    int iters = (end - beg + 7) >> 3;
    int io = __shfl(iters, lane ^ 32);
    int mi = iters > io ? iters : io;

    for (int it = 0; it < mi; ++it) {
        int base = beg + it * 8;
        if (base < end) {
            int q = base + (lane & 7);
            int sv = srcs[q < end ? q : end - 1];
            float pel = (q < end) ? __expf(leaky(al2s[sv] + dn)) : 0.f;
            int sj[8];
#pragma unroll
            for (int j = 0; j < 8; ++j) sj[j] = __shfl(sv, half + j);
            unsigned hv[8];
#pragma unroll
            for (int j = 0; j < 8; ++j)
                hv[j] = *(const unsigned short*)(xq + (size_t)sj[j] * 64 + cl * 2);
#pragma unroll
            for (int j = 0; j < 8; ++j) {
                float pj = __shfl(pel, half + j);
                den += pj;
                acc0 += pj * dec8(hv[j] & 0xffu);
                acc1 += pj * dec8(hv[j] >> 8);
            }
        }
    }
    if (alive) {
        float g0 = acc0 / den, g1 = acc1 / den;
        unsigned pk = (unsigned)(unsigned short)bfr(g0) | ((unsigned)(unsigned short)bfr(g1) << 16);
        *(unsigned*)((unsigned short*)gq + (size_t)n * 64 + cl * 2) = pk;
    }
}

// ---------------- gemm2b (MFMA, packed W2): out = logsoftmax(gq @ W2 + b2) -----------
__global__ __launch_bounds__(256) void gemm2b_kernel(
    const short* __restrict__ gq, const short* __restrict__ W2P,
    const float* __restrict__ b2, float* __restrict__ out, int N)
{
    const int l = threadIdx.x & 63, wv = threadIdx.x >> 6;
    const int m = l & 15, g = l >> 4;
    const int arow = blockIdx.x * 64 + wv * 16 + m;
    const bool rv = arow < N;

    f32x4 acc[3] = {f32x4{0,0,0,0}, f32x4{0,0,0,0}, f32x4{0,0,0,0}};

#pragma unroll
    for (int ks = 0; ks < 2; ++ks) {
        const int k0 = ks * 32 + g * 8;
        short8 af = short8{0,0,0,0,0,0,0,0};
        if (rv) af = *(const short8*)(gq + (size_t)arow * 64 + k0);
#pragma unroll
        for (int nt = 0; nt < 3; ++nt) {
            short8 bf_ = *(const short8*)(W2P + ((ks * 3 + nt) * 64 + l) * 8);
            acc[nt] = __builtin_amdgcn_mfma_f32_16x16x32_bf16(af, bf_, acc[nt], 0, 0, 0);
        }
    }

    // epilogue: bias + row log-softmax (row-group = 16 consecutive lanes, same g)
    const int orow0 = blockIdx.x * 64 + wv * 16 + g * 4;
    float bb[3];
#pragma unroll
    for (int nt = 0; nt < 3; ++nt) {
        int c = nt * 16 + m;
        bb[nt] = (c < 40) ? b2[c] : 0.f;
    }
    bool v2ok = (m < 8);                 // col 32+m valid only when m<8
#pragma unroll
    for (int r = 0; r < 4; ++r) {
        float v0 = acc[0][r] + bb[0];
        float v1 = acc[1][r] + bb[1];
        float v2 = v2ok ? acc[2][r] + bb[2] : -INFINITY;
        float mx = fmaxf(fmaxf(v0, v1), v2);
#pragma unroll
        for (int off = 1; off < 16; off <<= 1) mx = fmaxf(mx, __shfl_xor(mx, off));
        float s = __expf(v0 - mx) + __expf(v1 - mx) + (v2ok ? __expf(v2 - mx) : 0.f);
#pragma unroll
        for (int off = 1; off < 16; off <<= 1) s += __shfl_xor(s, off);
        float lse = mx + logf(s);
        int row = orow0 + r;
        if (row < N) {
            out[(size_t)row * 40 + m] = v0 - lse;
            out[(size_t)row * 40 + 16 + m] = v1 - lse;
            if (v2ok) out[(size_t)row * 40 + 32 + m] = v2 - lse;
        }
    }
}

extern "C" void kernel_launch(void* const* d_in, const int* in_sizes, int n_in,
                              void* d_out, int out_size, void* d_ws, size_t ws_size,
                              hipStream_t stream)
{
    const float*    x    = (const float*)d_in[0];
    const unsigned* eraw = (const unsigned*)d_in[1];
    const float*    W1   = (const float*)d_in[2];
    const float*    as1  = (const float*)d_in[3];
    const float*    ad1  = (const float*)d_in[4];
    const float*    b1   = (const float*)d_in[5];
    const float*    W2   = (const float*)d_in[6];
    const float*    as2  = (const float*)d_in[7];
    const float*    ad2  = (const float*)d_in[8];
    const float*    b2   = (const float*)d_in[9];
    float* out = (float*)d_out;

    const int N = in_sizes[0] / 256;
    const int E = in_sizes[1] / 2;
    const int NBK = (N + 1023) >> 10;      // 1024-node buckets (<= MAXBK)

    char* ws = (char*)d_ws;
    size_t off = 0;
    auto alloc = [&](size_t bytes) {
        size_t o = off;
        off = (off + bytes + 255) & ~(size_t)255;
        return o;
    };
    int*      ssorted = (int*)     (ws + alloc((size_t)E * 4));
    unsigned* stage   = (unsigned*)(ws + alloc((size_t)MAXBK * CAP * 4));
    int*      rowptr  = (int*)     (ws + alloc((size_t)(N + 1) * 4));
    int*      gcur    = (int*)     (ws + alloc((size_t)MAXBK * 4));
    int*      bb      = (int*)     (ws + alloc((size_t)(MAXBK + 1) * 4));
    int*      flag    = (int*)     (ws + alloc(256));
    short*    W1P     = (short*)   (ws + alloc((size_t)32 * 64 * 8 * 2));
    short*    W2P     = (short*)   (ws + alloc((size_t)6 * 64 * 8 * 2));
    unsigned char* h1q = (unsigned char*)(ws + alloc((size_t)N * 64));
    unsigned char* xq  = (unsigned char*)(ws + alloc((size_t)N * 64));
    short*    gq      = (short*)   (ws + alloc((size_t)N * 64 * 2));
    short*    als1h   = (short*)   (ws + alloc((size_t)N * 8 * 2));
    float*    ald1    = (float*)   (ws + alloc((size_t)N * 8 * 4));
    float*    al2s    = (float*)   (ws + alloc((size_t)N * 4));
    float*    al2d    = (float*)   (ws + alloc((size_t)N * 4));
    float*    w2a     = (float*)   (ws + alloc(64 * 4));
    float*    w2d     = (float*)   (ws + alloc(64 * 4));

    dim3 B(256);
    setup_kernel<<<dim3(78), B, 0, stream>>>(W1, W2, as2, ad2, eraw,
                                             W1P, W2P, w2a, w2d, flag, gcur);

    // [scat1' || gemm1] fused; scat blocks first for co-residency
    const int G1 = (N + 127) / 128;
    fused1_kernel<<<dim3(NWG + G1), B, 0, stream>>>(
        x, W1P, as1, ad1, h1q, als1h, ald1, N,
        eraw, flag, gcur, stage, NBK, E);

    tinyscan_kernel<<<1, dim3(64), 0, stream>>>(gcur, bb, NBK);
    scat2_kernel<<<dim3(NBK), dim3(1024), 0, stream>>>(stage, gcur, bb, rowptr, ssorted, NBK, N);

    agg1_kernel<<<dim3((N + 7) / 8), B, 0, stream>>>(rowptr, ssorted, h1q, als1h, ald1,
                                                     b1, w2a, w2d, xq, al2s, al2d, N);
    agg2_kernel<<<dim3((N + 7) / 8), B, 0, stream>>>(rowptr, ssorted, xq, al2s, al2d, gq, N);
    gemm2b_kernel<<<dim3((N + 63) / 64), B, 0, stream>>>(gq, W2P, b2, out, N);
}

// Round 23
// 159.710 us; speedup vs baseline: 1.0874x; 1.0874x over previous
//
#include <hip/hip_runtime.h>
#include <hip/hip_bf16.h>
#include <math.h>

#define NEG_SLOPE 0.2f
#define PACK_SHIFT 22
#define PACK_MASK ((1u << PACK_SHIFT) - 1u)
#define NWG 256          // WGs for bucket scatter
#define MAXBK 128        // max buckets (N <= 131072)
#define CAP 32768        // per-bucket staging capacity (expected ~16.4K)

typedef __attribute__((ext_vector_type(8))) short short8;
typedef __attribute__((ext_vector_type(4))) float f32x4;

__device__ __forceinline__ float leaky(float v) { return v >= 0.f ? v : NEG_SLOPE * v; }

// fp32 -> bf16 RNE (bit trick, finite inputs)
__device__ __forceinline__ short bfr(float f)
{
    union { float f; unsigned u; } v; v.f = f;
    unsigned r = (v.u + 0x7FFFu + ((v.u >> 16) & 1u)) >> 16;
    return (short)r;
}
// bf16 bits -> fp32
__device__ __forceinline__ float b2f(short s)
{
    union { unsigned u; float f; } v; v.u = ((unsigned)(unsigned short)s) << 16;
    return v.f;
}

// fp32 -> OCP e4m3fn (RNE, clamp 448, FTZ-free subnormals)
__device__ __forceinline__ unsigned char enc8(float f)
{
    union { float f; unsigned u; } v; v.f = f;
    unsigned s = (v.u >> 24) & 0x80u;
    v.u &= 0x7FFFFFFFu;
    if (v.f >= 448.f) return (unsigned char)(s | 0x7Eu);       // 448
    if (v.f < 0.015625f) {                                     // subnormal: k * 2^-9
        int mm = (int)rintf(v.f * 512.f);                      // 0..8 (8 carries to 2^-6)
        return (unsigned char)(s | (unsigned)mm);
    }
    unsigned u = v.u + 0x7FFFFu + ((v.u >> 20) & 1u);          // RNE to 3-bit mantissa
    unsigned e = ((u >> 23) & 0xFFu) - 120u;
    unsigned m = (u >> 20) & 7u;
    return (unsigned char)(s | (e << 3) | m);
}

// e4m3fn -> fp32
__device__ __forceinline__ float dec8(unsigned b)
{
#if __has_builtin(__builtin_amdgcn_cvt_f32_fp8)
    return __builtin_amdgcn_cvt_f32_fp8((int)b, 0);
#else
    unsigned s = (b & 0x80u) << 24, em = b & 0x7Fu;
    union { unsigned u; float f; } n; n.u = s | (((em >> 3) + 120u) << 23) | ((em & 7u) << 20);
    union { unsigned u; float f; } t; t.f = (float)em * 0.001953125f; t.u |= s;
    return em >= 8u ? n.f : t.f;
#endif
}

// ---------------- setup: W1/W2 fragment-packed bf16, w2a/w2d, detect, gcur ----------
// W1P[((ks*4+nt)*64 + lane)*8 + j] = bf16(W1[(ks*32+(lane>>4)*8+j)*64 + nt*16+(lane&15)])
// W2P[((ks*3+nt)*64 + lane)*8 + j] = bf16(W2[(ks*32+(lane>>4)*8+j)*40 + nt*16+(lane&15)])
__global__ void setup_kernel(const float* __restrict__ W1, const float* __restrict__ W2,
                             const float* __restrict__ as2, const float* __restrict__ ad2,
                             const unsigned* __restrict__ eraw,
                             short* __restrict__ W1P, short* __restrict__ W2P,
                             float* __restrict__ w2a, float* __restrict__ w2d,
                             int* __restrict__ flag, int* __restrict__ gcur)
{
    int bid = blockIdx.x, t = threadIdx.x;
    if (bid < 64) {                       // W1P: 16384 shorts
        int id = bid * 256 + t;
        int j = id & 7, l = (id >> 3) & 63, fr = id >> 9;
        int ks = fr >> 2, nt = fr & 3;
        int k = ks * 32 + (l >> 4) * 8 + j;
        int c = nt * 16 + (l & 15);
        W1P[id] = bfr(W1[k * 64 + c]);
    } else if (bid < 76) {                // W2P: 3072 shorts (12 blocks)
        int id = (bid - 64) * 256 + t;
        if (id < 3072) {
            int j = id & 7, l = (id >> 3) & 63, fr = id >> 9;
            int ks = fr / 3, nt = fr - ks * 3;
            int k = ks * 32 + (l >> 4) * 8 + j;
            int c = nt * 16 + (l & 15);
            W2P[id] = (c < 40) ? bfr(W2[k * 40 + c]) : (short)0;
        }
    } else if (bid == 76) {               // w2a/w2d + gcur zero
        if (t < 64) {
            float a = 0.f, d = 0.f;
            for (int c = 0; c < 40; ++c) {
                float w = W2[t * 40 + c];
                a += w * as2[c];
                d += w * ad2[c];
            }
            w2a[t] = a; w2d[t] = d;
        } else if (t < 64 + MAXBK) {
            gcur[t - 64] = 0;
        }
    } else {                              // detect int64 vs int32 edge layout
        __shared__ int anynz;
        if (t == 0) anynz = 0;
        __syncthreads();
        bool nz = false;
#pragma unroll
        for (int j = 0; j < 8; ++j) {
            int idx = 2 * (t + 256 * j) + 1;
            nz |= (eraw[idx] != 0u);
        }
        if (nz) anynz = 1;
        __syncthreads();
        if (t == 0) *flag = anynz ? 0 : 1;     // 1 => int64 layout
    }
}

// ---------------- fused1: blocks [0,NWG) = scat1' (hist+reserve+scatter);
// ----------------         blocks [NWG,..) = gemm1 (MFMA, A in LDS, B packed global) --
__global__ __launch_bounds__(256) void fused1_kernel(
    // gemm1 args
    const float* __restrict__ x, const short* __restrict__ W1P,
    const float* __restrict__ as1, const float* __restrict__ ad1,
    unsigned char* __restrict__ h1q, short* __restrict__ als1h,
    float* __restrict__ ald1, int N,
    // scat1' args
    const unsigned* __restrict__ eraw, const int* __restrict__ flag,
    int* __restrict__ gcur, unsigned* __restrict__ stage, int NBK, int E)
{
    __shared__ short xsb[64 * 128];       // 16 KB: x K-half bf16, slot^=(row&7); reused for epilogue
    __shared__ int cnt[MAXBK];
    __shared__ int st[MAXBK];
    const int t = threadIdx.x;

    if (blockIdx.x < NWG) {
        // ---- scat1': one-pass bucket scatter with per-WG range reservation ----
        int wg = blockIdx.x;
        if (t < NBK) cnt[t] = 0;
        __syncthreads();
        int f = *flag;
        int chunk = (E + NWG - 1) / NWG;
        int lo = wg * chunk;
        int hi = lo + chunk; if (hi > E) hi = E;
        for (int e = lo + t; e < hi; e += 256) {
            int dst = (int)(f ? eraw[2 * (E + e)] : eraw[E + e]);
            atomicAdd(&cnt[dst >> 10], 1);
        }
        __syncthreads();
        if (t < NBK) {
            int c = cnt[t];
            st[t] = t * CAP + atomicAdd(&gcur[t], c);
            cnt[t] = 0;
        }
        __syncthreads();
        for (int e = lo + t; e < hi; e += 256) {
            unsigned src = f ? eraw[2 * e] : eraw[e];
            unsigned dst = f ? eraw[2 * (E + e)] : eraw[E + e];
            int b = (int)(dst >> 10);
            int k = atomicAdd(&cnt[b], 1);
            int pos = st[b] + k;
            if (pos < (b + 1) * CAP)      // safety clamp (never hit for uniform graphs)
                stage[pos] = src | ((dst & 1023u) << PACK_SHIFT);
        }
        return;
    }

    // ---- gemm1 ----
    const int bid = blockIdx.x - NWG;
    const int l = t & 63, wv = t >> 6;
    const int m = l & 15, g = l >> 4;
    const int row0 = bid * 64;

    f32x4 acc[4] = {f32x4{0,0,0,0}, f32x4{0,0,0,0}, f32x4{0,0,0,0}, f32x4{0,0,0,0}};
    const int arl = wv * 16 + m;          // local A row (arl&7 == m&7)

    for (int kc = 0; kc < 2; ++kc) {
        // stage x half: 64 rows x 16 slots (slot = 8 floats -> 8 bf16)
#pragma unroll
        for (int j = 0; j < 4; ++j) {
            int idx = t + 256 * j;
            int r = idx >> 4, s = idx & 15;
            int row = row0 + r;
            short8 v8 = short8{0,0,0,0,0,0,0,0};
            if (row < N) {
                const float* p = x + (size_t)row * 256 + kc * 128 + s * 8;
                float4 a = *(const float4*)p;
                float4 b = *(const float4*)(p + 4);
                v8[0] = bfr(a.x); v8[1] = bfr(a.y); v8[2] = bfr(a.z); v8[3] = bfr(a.w);
                v8[4] = bfr(b.x); v8[5] = bfr(b.y); v8[6] = bfr(b.z); v8[7] = bfr(b.w);
            }
            int sw = s ^ (r & 7);
            *(short8*)&xsb[r * 128 + sw * 8] = v8;
        }
        __syncthreads();
#pragma unroll
        for (int ksub = 0; ksub < 4; ++ksub) {
            const int ks = kc * 4 + ksub;
            const int sA = (ksub * 4 + g) ^ (m & 7);
            short8 af = *(const short8*)&xsb[arl * 128 + sA * 8];
#pragma unroll
            for (int nt = 0; nt < 4; ++nt) {
                short8 bf_ = *(const short8*)(W1P + ((ks * 4 + nt) * 64 + l) * 8);
                acc[nt] = __builtin_amdgcn_mfma_f32_16x16x32_bf16(af, bf_, acc[nt], 0, 0, 0);
            }
        }
        __syncthreads();
    }

    // epilogue 1: per-head attention logits
    const int orow0 = row0 + wv * 16 + g * 4;
    float a_sv[4], a_dv[4];
#pragma unroll
    for (int nt = 0; nt < 4; ++nt) { a_sv[nt] = as1[nt * 16 + m]; a_dv[nt] = ad1[nt * 16 + m]; }

    float vs[4][4], vd[4][4];
#pragma unroll
    for (int nt = 0; nt < 4; ++nt)
#pragma unroll
        for (int r = 0; r < 4; ++r) {
            vs[nt][r] = acc[nt][r] * a_sv[nt];
            vd[nt][r] = acc[nt][r] * a_dv[nt];
        }
#pragma unroll
    for (int off = 1; off < 8; off <<= 1)
#pragma unroll
        for (int nt = 0; nt < 4; ++nt)
#pragma unroll
            for (int r = 0; r < 4; ++r) {
                vs[nt][r] += __shfl_xor(vs[nt][r], off);
                vd[nt][r] += __shfl_xor(vd[nt][r], off);
            }

    // epilogue 2: fp8 features via LDS bounce -> coalesced 16B stores
    unsigned char* hb = (unsigned char*)xsb;   // 4KB region (safe: all compute reads done)
#pragma unroll
    for (int nt = 0; nt < 4; ++nt)
#pragma unroll
        for (int r = 0; r < 4; ++r)
            hb[(wv * 16 + g * 4 + r) * 64 + nt * 16 + m] = enc8(acc[nt][r]);
    __syncthreads();
    {
        int r = t >> 2, part = t & 3;
        int row = row0 + r;
        if (row < N)
            *(uint4*)(h1q + (size_t)row * 64 + part * 16) = *(const uint4*)&hb[r * 64 + part * 16];
    }

    if ((l & 7) == 0) {
        int par = m >> 3;
#pragma unroll
        for (int nt = 0; nt < 4; ++nt)
#pragma unroll
            for (int r = 0; r < 4; ++r) {
                int row = orow0 + r;
                if (row < N) {
                    als1h[row * 8 + 2 * nt + par] = bfr(vs[nt][r]);
                    ald1[row * 8 + 2 * nt + par] = vd[nt][r];
                }
            }
    }
}

// ---------------- tinyscan: prefix over bucket totals -> bb -------------------------
__global__ void tinyscan_kernel(const int* __restrict__ gcur, int* __restrict__ bb, int NBK)
{
    int lane = threadIdx.x;               // 64 threads
    int v0 = (lane < NBK) ? min(gcur[lane], CAP) : 0;
    int v1 = (lane + 64 < NBK) ? min(gcur[lane + 64], CAP) : 0;
    int s0 = v0;
#pragma unroll
    for (int off = 1; off < 64; off <<= 1) { int u = __shfl_up(s0, off); if (lane >= off) s0 += u; }
    int tot0 = __shfl(s0, 63);
    if (lane < NBK) bb[lane] = s0 - v0;
    int s1 = v1;
#pragma unroll
    for (int off = 1; off < 64; off <<= 1) { int u = __shfl_up(s1, off); if (lane >= off) s1 += u; }
    if (lane + 64 < NBK) bb[lane + 64] = tot0 + s1 - v1;
    int tot1 = __shfl(s1, 63);
    if (lane == 0) bb[NBK] = tot0 + tot1;
}

// ---------------- scat2: per bucket: LDS count + scan -> rowptr; place ssorted -------
__global__ __launch_bounds__(1024) void scat2_kernel(
    const unsigned* __restrict__ stage, const int* __restrict__ gcur,
    const int* __restrict__ bb, int* __restrict__ rowptr, int* __restrict__ ssorted,
    int NBK, int N)
{
    __shared__ int cnt[1024];
    __shared__ int sc[1024];
    __shared__ int wt[16];
    int b = blockIdx.x, i = threadIdx.x;
    int cntb = min(gcur[b], CAP);
    int basein = b * CAP;
    int baseout = bb[b];
    int node0 = b << 10;
    int nvalid = N - node0; if (nvalid > 1024) nvalid = 1024;
    cnt[i] = 0;
    __syncthreads();
    for (int p = i; p < cntb; p += 1024)
        atomicAdd(&cnt[stage[basein + p] >> PACK_SHIFT], 1);
    __syncthreads();
    int v = cnt[i];
    int lane = i & 63, wv = i >> 6;
    int incl = v;
#pragma unroll
    for (int off = 1; off < 64; off <<= 1) { int u = __shfl_up(incl, off); if (lane >= off) incl += u; }
    if (lane == 63) wt[wv] = incl;
    __syncthreads();
    int wbase = 0;
    for (int w = 0; w < wv; ++w) wbase += wt[w];
    int excl = wbase + incl - v;
    sc[i] = excl;
    if (i < nvalid) rowptr[node0 + i] = baseout + excl;
    if (b == NBK - 1 && i == 0) rowptr[N] = bb[NBK];
    cnt[i] = 0;
    __syncthreads();
    for (int p = i; p < cntb; p += 1024) {
        unsigned w = stage[basein + p];
        int d = (int)(w >> PACK_SHIFT);
        int k = atomicAdd(&cnt[d], 1);
        ssorted[baseout + sc[d] + k] = (int)(w & PACK_MASK);
    }
}

// ---------------- agg1: 2 nodes/wave (ushort fp8-pair lanes) -> xq fp8 + logits ------
__global__ __launch_bounds__(256) void agg1_kernel(
    const int* __restrict__ rowptr, const int* __restrict__ srcs,
    const unsigned char* __restrict__ h1q, const short* __restrict__ als1h,
    const float* __restrict__ ald1, const float* __restrict__ b1,
    const float* __restrict__ w2a, const float* __restrict__ w2d,
    unsigned char* __restrict__ xq, float* __restrict__ al2s, float* __restrict__ al2d, int N)
{
    int t = threadIdx.x, lane = t & 63, w = t >> 6;
    int half = lane & 32;
    int cl = lane & 31;                 // channel pair index
    int n = blockIdx.x * 8 + w * 2 + (lane >> 5);
    bool alive = n < N;
    int nn = alive ? n : 0;
    int hb = cl >> 2;                   // head of channels 2cl,2cl+1
    int ph = lane & 7;                  // pe head this lane computes
    int pes = (lane >> 3) & 3;          // pe edge sub-slot

    float aldn = ald1[nn * 8 + hb];
    float aldl = ald1[nn * 8 + ph];
    float alsn = b2f(als1h[nn * 8 + hb]);
    float p = __expf(leaky(alsn + aldn));
    float den = p;
    unsigned hv0 = *(const unsigned short*)(h1q + (size_t)nn * 64 + cl * 2);
    float acc0 = p * dec8(hv0 & 0xffu);
    float acc1 = p * dec8(hv0 >> 8);

    int beg = alive ? rowptr[nn] : 0;
    int end = alive ? rowptr[nn + 1] : 0;
    int iters = (end - beg + 7) >> 3;
    int io = __shfl(iters, lane ^ 32);
    int mi = iters > io ? iters : io;

    for (int it = 0; it < mi; ++it) {
        int base = beg + it * 8;
        if (base < end) {
            int q = base + (lane & 7);
            int sv = srcs[q < end ? q : end - 1];
            float pel0, pel1;
            {
                int srcl = __shfl(sv, half + pes);
                float av = b2f(als1h[srcl * 8 + ph]);
                pel0 = (base + pes < end) ? __expf(leaky(av + aldl)) : 0.f;
            }
            {
                int srcl = __shfl(sv, half + 4 + pes);
                float av = b2f(als1h[srcl * 8 + ph]);
                pel1 = (base + 4 + pes < end) ? __expf(leaky(av + aldl)) : 0.f;
            }
            int sj[8];
#pragma unroll
            for (int j = 0; j < 8; ++j) sj[j] = __shfl(sv, half + j);
            unsigned hv[8];
#pragma unroll
            for (int j = 0; j < 8; ++j)
                hv[j] = *(const unsigned short*)(h1q + (size_t)sj[j] * 64 + cl * 2);
#pragma unroll
            for (int j = 0; j < 8; ++j) {
                float pj = __shfl(j < 4 ? pel0 : pel1, half + ((j & 3) << 3) + hb);
                den += pj;
                acc0 += pj * dec8(hv[j] & 0xffu);
                acc1 += pj * dec8(hv[j] >> 8);
            }
        }
    }
    if (alive) {
        float2 bb = *(const float2*)(b1 + cl * 2);
        float v0 = acc0 / den + bb.x;
        float v1 = acc1 / den + bb.y;
        float x0 = v0 > 0.f ? v0 : expm1f(v0);
        float x1 = v1 > 0.f ? v1 : expm1f(v1);
        unsigned pk = (unsigned)enc8(x0) | ((unsigned)enc8(x1) << 8);
        *(unsigned short*)(xq + (size_t)n * 64 + cl * 2) = (unsigned short)pk;
        float2 wa = *(const float2*)(w2a + cl * 2);
        float2 wd = *(const float2*)(w2d + cl * 2);
        float sa = x0 * wa.x + x1 * wa.y;
        float sd = x0 * wd.x + x1 * wd.y;
#pragma unroll
        for (int off = 1; off < 32; off <<= 1) {
            sa += __shfl_xor(sa, off);
            sd += __shfl_xor(sd, off);
        }
        if (cl == 0) { al2s[n] = sa; al2d[n] = sd; }
    }
}

// ---------------- agg2: 2 nodes/wave aggregate xq (fp8) -> gq bf16 -------------------
__global__ __launch_bounds__(256) void agg2_kernel(
    const int* __restrict__ rowptr, const int* __restrict__ srcs,
    const unsigned char* __restrict__ xq,
    const float* __restrict__ al2s, const float* __restrict__ al2d,
    short* __restrict__ gq, int N)
{
    int t = threadIdx.x, lane = t & 63, w = t >> 6;
    int half = lane & 32;
    int cl = lane & 31;
    int n = blockIdx.x * 8 + w * 2 + (lane >> 5);
    bool alive = n < N;
    int nn = alive ? n : 0;

    float dn = al2d[nn];
    float p = __expf(leaky(al2s[nn] + dn));
    float den = p;
    unsigned hv0 = *(const unsigned short*)(xq + (size_t)nn * 64 + cl * 2);
    float acc0 = p * dec8(hv0 & 0xffu);
    float acc1 = p * dec8(hv0 >> 8);

    int beg = alive ? rowptr[nn] : 0;
    int end = alive ? rowptr[nn + 1] : 0;
    int iters = (end - beg + 7) >> 3;
    int io = __shfl(iters, lane ^ 32);
    int mi = iters > io ? iters : io;

    for (int it = 0; it < mi; ++it) {
        int base = beg + it * 8;
        if (base < end) {
            int q = base + (lane & 7);
            int sv = srcs[q < end ? q : end - 1];
            float pel = (q < end) ? __expf(leaky(al2s[sv] + dn)) : 0.f;
            int sj[8];
#pragma unroll
            for (int j = 0; j < 8; ++j) sj[j] = __shfl(sv, half + j);
            unsigned hv[8];
#pragma unroll
            for (int j = 0; j < 8; ++j)
                hv[j] = *(const unsigned short*)(xq + (size_t)sj[j] * 64 + cl * 2);
#pragma unroll
            for (int j = 0; j < 8; ++j) {
                float pj = __shfl(pel, half + j);
                den += pj;
                acc0 += pj * dec8(hv[j] & 0xffu);
                acc1 += pj * dec8(hv[j] >> 8);
            }
        }
    }
    if (alive) {
        float g0 = acc0 / den, g1 = acc1 / den;
        unsigned pk = (unsigned)(unsigned short)bfr(g0) | ((unsigned)(unsigned short)bfr(g1) << 16);
        *(unsigned*)((unsigned short*)gq + (size_t)n * 64 + cl * 2) = pk;
    }
}

// ---------------- gemm2b (MFMA, packed W2): out = logsoftmax(gq @ W2 + b2) -----------
__global__ __launch_bounds__(256) void gemm2b_kernel(
    const short* __restrict__ gq, const short* __restrict__ W2P,
    const float* __restrict__ b2, float* __restrict__ out, int N)
{
    const int l = threadIdx.x & 63, wv = threadIdx.x >> 6;
    const int m = l & 15, g = l >> 4;
    const int arow = blockIdx.x * 64 + wv * 16 + m;
    const bool rv = arow < N;

    f32x4 acc[3] = {f32x4{0,0,0,0}, f32x4{0,0,0,0}, f32x4{0,0,0,0}};

#pragma unroll
    for (int ks = 0; ks < 2; ++ks) {
        const int k0 = ks * 32 + g * 8;
        short8 af = short8{0,0,0,0,0,0,0,0};
        if (rv) af = *(const short8*)(gq + (size_t)arow * 64 + k0);
#pragma unroll
        for (int nt = 0; nt < 3; ++nt) {
            short8 bf_ = *(const short8*)(W2P + ((ks * 3 + nt) * 64 + l) * 8);
            acc[nt] = __builtin_amdgcn_mfma_f32_16x16x32_bf16(af, bf_, acc[nt], 0, 0, 0);
        }
    }

    // epilogue: bias + row log-softmax (row-group = 16 consecutive lanes, same g)
    const int orow0 = blockIdx.x * 64 + wv * 16 + g * 4;
    float bb[3];
#pragma unroll
    for (int nt = 0; nt < 3; ++nt) {
        int c = nt * 16 + m;
        bb[nt] = (c < 40) ? b2[c] : 0.f;
    }
    bool v2ok = (m < 8);                 // col 32+m valid only when m<8
#pragma unroll
    for (int r = 0; r < 4; ++r) {
        float v0 = acc[0][r] + bb[0];
        float v1 = acc[1][r] + bb[1];
        float v2 = v2ok ? acc[2][r] + bb[2] : -INFINITY;
        float mx = fmaxf(fmaxf(v0, v1), v2);
#pragma unroll
        for (int off = 1; off < 16; off <<= 1) mx = fmaxf(mx, __shfl_xor(mx, off));
        float s = __expf(v0 - mx) + __expf(v1 - mx) + (v2ok ? __expf(v2 - mx) : 0.f);
#pragma unroll
        for (int off = 1; off < 16; off <<= 1) s += __shfl_xor(s, off);
        float lse = mx + logf(s);
        int row = orow0 + r;
        if (row < N) {
            out[(size_t)row * 40 + m] = v0 - lse;
            out[(size_t)row * 40 + 16 + m] = v1 - lse;
            if (v2ok) out[(size_t)row * 40 + 32 + m] = v2 - lse;
        }
    }
}

extern "C" void kernel_launch(void* const* d_in, const int* in_sizes, int n_in,
                              void* d_out, int out_size, void* d_ws, size_t ws_size,
                              hipStream_t stream)
{
    const float*    x    = (const float*)d_in[0];
    const unsigned* eraw = (const unsigned*)d_in[1];
    const float*    W1   = (const float*)d_in[2];
    const float*    as1  = (const float*)d_in[3];
    const float*    ad1  = (const float*)d_in[4];
    const float*    b1   = (const float*)d_in[5];
    const float*    W2   = (const float*)d_in[6];
    const float*    as2  = (const float*)d_in[7];
    const float*    ad2  = (const float*)d_in[8];
    const float*    b2   = (const float*)d_in[9];
    float* out = (float*)d_out;

    const int N = in_sizes[0] / 256;
    const int E = in_sizes[1] / 2;
    const int NBK = (N + 1023) >> 10;      // 1024-node buckets (<= MAXBK)

    char* ws = (char*)d_ws;
    size_t off = 0;
    auto alloc = [&](size_t bytes) {
        size_t o = off;
        off = (off + bytes + 255) & ~(size_t)255;
        return o;
    };
    int*      ssorted = (int*)     (ws + alloc((size_t)E * 4));
    unsigned* stage   = (unsigned*)(ws + alloc((size_t)MAXBK * CAP * 4));
    int*      rowptr  = (int*)     (ws + alloc((size_t)(N + 1) * 4));
    int*      gcur    = (int*)     (ws + alloc((size_t)MAXBK * 4));
    int*      bb      = (int*)     (ws + alloc((size_t)(MAXBK + 1) * 4));
    int*      flag    = (int*)     (ws + alloc(256));
    short*    W1P     = (short*)   (ws + alloc((size_t)32 * 64 * 8 * 2));
    short*    W2P     = (short*)   (ws + alloc((size_t)6 * 64 * 8 * 2));
    unsigned char* h1q = (unsigned char*)(ws + alloc((size_t)N * 64));
    unsigned char* xq  = (unsigned char*)(ws + alloc((size_t)N * 64));
    short*    gq      = (short*)   (ws + alloc((size_t)N * 64 * 2));
    short*    als1h   = (short*)   (ws + alloc((size_t)N * 8 * 2));
    float*    ald1    = (float*)   (ws + alloc((size_t)N * 8 * 4));
    float*    al2s    = (float*)   (ws + alloc((size_t)N * 4));
    float*    al2d    = (float*)   (ws + alloc((size_t)N * 4));
    float*    w2a     = (float*)   (ws + alloc(64 * 4));
    float*    w2d     = (float*)   (ws + alloc(64 * 4));

    dim3 B(256);
    setup_kernel<<<dim3(78), B, 0, stream>>>(W1, W2, as2, ad2, eraw,
                                             W1P, W2P, w2a, w2d, flag, gcur);

    // [scat1' || gemm1] fused; scat blocks first for co-residency
    const int G1 = (N + 63) / 64;
    fused1_kernel<<<dim3(NWG + G1), B, 0, stream>>>(
        x, W1P, as1, ad1, h1q, als1h, ald1, N,
        eraw, flag, gcur, stage, NBK, E);

    tinyscan_kernel<<<1, dim3(64), 0, stream>>>(gcur, bb, NBK);
    scat2_kernel<<<dim3(NBK), dim3(1024), 0, stream>>>(stage, gcur, bb, rowptr, ssorted, NBK, N);

    agg1_kernel<<<dim3((N + 7) / 8), B, 0, stream>>>(rowptr, ssorted, h1q, als1h, ald1,
                                                     b1, w2a, w2d, xq, al2s, al2d, N);
    agg2_kernel<<<dim3((N + 7) / 8), B, 0, stream>>>(rowptr, ssorted, xq, al2s, al2d, gq, N);
    gemm2b_kernel<<<dim3((N + 63) / 64), B, 0, stream>>>(gq, W2P, b2, out, N);
}